// Round 9
// baseline (189.868 us; speedup 1.0000x reference)
//
#include <hip/hip_runtime.h>
#include <hip/hip_bf16.h>
#include <hip/hip_fp16.h>
#include <math.h>

// ---- problem constants (structural, from the reference) ----
#define NB      2
#define QN      12240
#define HW_TOT  12240
#define DIMS    256
#define HEADS   8
#define CH      32
#define LEVELS  4
#define POINTS  4
#define M_TOT   (NB * QN)        // 24480

typedef unsigned short ushort_t;
typedef __attribute__((ext_vector_type(8))) short short8;
typedef __attribute__((ext_vector_type(4))) float floatx4;

__device__ __forceinline__ ushort_t f2bf(float f) {
    __hip_bfloat16 h = __float2bfloat16(f);
    return *reinterpret_cast<ushort_t*>(&h);
}
__device__ __forceinline__ ushort_t f2h(float f) {
    __half h = __float2half(f);
    return *reinterpret_cast<ushort_t*>(&h);
}

#define GLOAD16(gp, lp) __builtin_amdgcn_global_load_lds( \
    (const __attribute__((address_space(1))) void*)(gp),  \
    (__attribute__((address_space(3))) void*)(lp), 16, 0, 0)

// =====================================================================
// Weights -> transposed bf16 (small, 384 blocks): Tin/Tout (gi<65536),
// Tcomb [384][256], combined bias, and the 128B zero pad after vproj.
// =====================================================================
__global__ __launch_bounds__(256) void prep_weights_kernel(
    const float* __restrict__ W_in, const float* __restrict__ W_off,
    const float* __restrict__ W_attn, const float* __restrict__ W_out,
    const float* __restrict__ b_off, const float* __restrict__ b_attn,
    ushort_t* __restrict__ Tin, ushort_t* __restrict__ Tcomb,
    ushort_t* __restrict__ Tout, float* __restrict__ bcomb,
    int* __restrict__ vpad)
{
    const int gi = blockIdx.x * 256 + threadIdx.x;   // grid = 384 blocks
    if (gi < 32)  vpad[gi] = 0;                      // 128B zero pad
    if (gi < 384) bcomb[gi] = (gi < 256) ? b_off[gi] : b_attn[gi - 256];
    const int k = gi & 255;                          // coalesced along k
    const int n = gi >> 8;
    if (gi < 65536) {
        Tin[n * 256 + k]  = f2bf(W_in[k * 256 + n]);
        Tout[n * 256 + k] = f2bf(W_out[k * 256 + n]);
    }
    const float val = (n < 256) ? W_off[k * 256 + n]
                                : W_attn[k * 128 + (n - 256)];
    Tcomb[n * 256 + k] = f2bf(val);
}

// =====================================================================
// Fused-convert GEMM tile (R6 single-buffer structure, unchanged).
// CMODE: 1 = FP16 HEAD-MAJOR vproj ((h*M+row)*32+ch), 2 = fp16 row-major.
// =====================================================================
template<int CMODE, bool DUAL>
__device__ __forceinline__ void gemm_fused_tile(
    const float* __restrict__ A32, const ushort_t* __restrict__ BT,
    const float* __restrict__ bias, void* __restrict__ C,
    int M, int Nc, int bm0, int bn0a, int bn0b,
    ushort_t* As, ushort_t* Bs0, ushort_t* Bs1)
{
    const int tid  = threadIdx.x;
    const int wave = tid >> 6;
    const int lane = tid & 63;
    const int quad = lane >> 4;
    const int l16  = lane & 15;
    const int wm   = (wave >> 1) * 64;
    const int wn   = (wave & 1) * 64;

    const int off0 = tid * 16;            // LDS byte offset (linear)
    const int row0 = off0 >> 6;           // 0..63 (64B = 32 bf16/row)
    const int kc0  = (off0 & 63) >> 1;    // element k-offset: 0/8/16/24

    int ar0 = bm0 + row0;      if (ar0 > M - 1) ar0 = M - 1;
    int ar1 = bm0 + row0 + 64; if (ar1 > M - 1) ar1 = M - 1;

    const float*    gA0  = A32 + (size_t)ar0 * 256 + kc0;
    const float*    gA1  = A32 + (size_t)ar1 * 256 + kc0;
    const ushort_t* gb0a = BT + (size_t)(bn0a + row0) * 256 + kc0;
    const ushort_t* gb1a = BT + (size_t)(bn0a + row0 + 64) * 256 + kc0;
    const ushort_t* gb0b = BT + (size_t)(bn0b + row0) * 256 + kc0;
    const ushort_t* gb1b = BT + (size_t)(bn0b + row0 + 64) * 256 + kc0;

    ushort_t* lB0a = Bs0 + wave * 512;
    ushort_t* lB1a = Bs0 + wave * 512 + 2048;
    ushort_t* lB0b = Bs1 + wave * 512;
    ushort_t* lB1b = Bs1 + wave * 512 + 2048;

    floatx4 acc0[4][4], acc1[4][4];
    #pragma unroll
    for (int i = 0; i < 4; ++i)
        #pragma unroll
        for (int j = 0; j < 4; ++j) {
            acc0[i][j] = (floatx4){0.f, 0.f, 0.f, 0.f};
            if (DUAL) acc1[i][j] = (floatx4){0.f, 0.f, 0.f, 0.f};
        }

    for (int kk = 0; kk < 256; kk += 32) {
        GLOAD16(gb0a + kk, lB0a);
        GLOAD16(gb1a + kk, lB1a);
        if (DUAL) {
            GLOAD16(gb0b + kk, lB0b);
            GLOAD16(gb1b + kk, lB1b);
        }
        // A: fp32 -> bf16 reg-staged (each thread: 2 rows x 8 elems)
        {
            const float4 a0 = *(const float4*)(gA0 + kk);
            const float4 a1 = *(const float4*)(gA0 + kk + 4);
            const float4 b0 = *(const float4*)(gA1 + kk);
            const float4 b1 = *(const float4*)(gA1 + kk + 4);
            ushort_t t0[8] = {f2bf(a0.x), f2bf(a0.y), f2bf(a0.z), f2bf(a0.w),
                              f2bf(a1.x), f2bf(a1.y), f2bf(a1.z), f2bf(a1.w)};
            ushort_t t1[8] = {f2bf(b0.x), f2bf(b0.y), f2bf(b0.z), f2bf(b0.w),
                              f2bf(b1.x), f2bf(b1.y), f2bf(b1.z), f2bf(b1.w)};
            *(int4*)&As[tid * 8]        = *(int4*)t0;
            *(int4*)&As[tid * 8 + 2048] = *(int4*)t1;
        }
        __syncthreads();

        short8 af[4], bfa[4], bfb[4];
        #pragma unroll
        for (int mt = 0; mt < 4; ++mt)
            af[mt] = *(const short8*)&As[(wm + mt * 16 + l16) * 32 + quad * 8];
        #pragma unroll
        for (int nt = 0; nt < 4; ++nt) {
            bfa[nt] = *(const short8*)&Bs0[(wn + nt * 16 + l16) * 32 + quad * 8];
            if (DUAL)
                bfb[nt] = *(const short8*)&Bs1[(wn + nt * 16 + l16) * 32 + quad * 8];
        }
        #pragma unroll
        for (int mt = 0; mt < 4; ++mt)
            #pragma unroll
            for (int nt = 0; nt < 4; ++nt) {
                acc0[mt][nt] = __builtin_amdgcn_mfma_f32_16x16x32_bf16(
                    af[mt], bfa[nt], acc0[mt][nt], 0, 0, 0);
                if (DUAL)
                    acc1[mt][nt] = __builtin_amdgcn_mfma_f32_16x16x32_bf16(
                        af[mt], bfb[nt], acc1[mt][nt], 0, 0, 0);
            }
        __syncthreads();
    }

    #pragma unroll
    for (int mt = 0; mt < 4; ++mt) {
        #pragma unroll
        for (int j = 0; j < 4; ++j) {
            const int row = bm0 + wm + mt * 16 + quad * 4 + j;
            if (row >= M) continue;
            #pragma unroll
            for (int nt = 0; nt < 4; ++nt) {
                {
                    const int col = bn0a + wn + nt * 16 + l16;
                    const float val = acc0[mt][nt][j] + bias[col];
                    if (CMODE == 1) {
                        const size_t idx = (((size_t)(col >> 5) * M + row) << 5) + (col & 31);
                        ((ushort_t*)C)[idx] = f2h(val);          // fp16 vproj
                    } else {
                        ((ushort_t*)C)[(size_t)row * Nc + col] = f2h(val);
                    }
                }
                if (DUAL) {
                    const int col = bn0b + wn + nt * 16 + l16;
                    const float val = acc1[mt][nt][j] + bias[col];
                    if (CMODE == 1) {
                        const size_t idx = (((size_t)(col >> 5) * M + row) << 5) + (col & 31);
                        ((ushort_t*)C)[idx] = f2h(val);          // fp16 vproj
                    } else {
                        ((ushort_t*)C)[(size_t)row * Nc + col] = f2h(val);
                    }
                }
            }
        }
    }
}

__global__ __launch_bounds__(256) void gemm_proj_kernel(
    const float* __restrict__ v, const float* __restrict__ q,
    const ushort_t* __restrict__ Tin, const ushort_t* __restrict__ Tcomb,
    const float* __restrict__ b_in, const float* __restrict__ bcomb,
    ushort_t* __restrict__ vproj, ushort_t* __restrict__ offh)
{
    __shared__ ushort_t As [128 * 32];
    __shared__ ushort_t Bs0[128 * 32];
    __shared__ ushort_t Bs1[128 * 32];
    const int bm0 = blockIdx.x * 128;
    const int y = blockIdx.y;
    if (y == 0)       // vproj = v @ W_in (fp16 head-major), both col-tiles
        gemm_fused_tile<1, true >(v, Tin,   b_in,  vproj, M_TOT, 256, bm0, 0, 128, As, Bs0, Bs1);
    else if (y == 1)  // offh cols 0-255 = q @ Tcomb (fp16)
        gemm_fused_tile<2, true >(q, Tcomb, bcomb, offh,  M_TOT, 384, bm0, 0, 128, As, Bs0, Bs1);
    else              // offh cols 256-383
        gemm_fused_tile<2, false>(q, Tcomb, bcomb, offh,  M_TOT, 384, bm0, 256, 0, As, Bs0, Bs1);
}

// =====================================================================
// m97-style bf16 GEMM for the output projection (unchanged).
// =====================================================================
__device__ __forceinline__ void gemm_tile_core(
    const ushort_t* __restrict__ A, const ushort_t* __restrict__ BT,
    const float* __restrict__ bias, float* __restrict__ C,
    int M, int Nc, int bm0, int bn0, int K,
    ushort_t* As, ushort_t* Bs)
{
    const int tid  = threadIdx.x;
    const int wave = tid >> 6;
    const int lane = tid & 63;
    const int quad = lane >> 4;
    const int l16  = lane & 15;
    const int wm   = (wave >> 1) * 64;
    const int wn   = (wave & 1) * 64;

    const int off0 = tid * 16;
    const int row0 = off0 >> 6;
    const int kc0  = (off0 & 63) >> 1;

    int ar0 = bm0 + row0;      if (ar0 > M - 1) ar0 = M - 1;
    int ar1 = bm0 + row0 + 64; if (ar1 > M - 1) ar1 = M - 1;

    const ushort_t* ga0 = A  + (size_t)ar0 * K + kc0;
    const ushort_t* ga1 = A  + (size_t)ar1 * K + kc0;
    const ushort_t* gb0 = BT + (size_t)(bn0 + row0) * K + kc0;
    const ushort_t* gb1 = BT + (size_t)(bn0 + row0 + 64) * K + kc0;

    ushort_t* lA0 = As + wave * 512;
    ushort_t* lA1 = As + wave * 512 + 2048;
    ushort_t* lB0 = Bs + wave * 512;
    ushort_t* lB1 = Bs + wave * 512 + 2048;

    floatx4 acc[4][4];
    #pragma unroll
    for (int i = 0; i < 4; ++i)
        #pragma unroll
        for (int j = 0; j < 4; ++j)
            acc[i][j] = (floatx4){0.f, 0.f, 0.f, 0.f};

    for (int kk = 0; kk < K; kk += 32) {
        GLOAD16(ga0 + kk, lA0);
        GLOAD16(ga1 + kk, lA1);
        GLOAD16(gb0 + kk, lB0);
        GLOAD16(gb1 + kk, lB1);
        __syncthreads();

        short8 af[4], bfr[4];
        #pragma unroll
        for (int mt = 0; mt < 4; ++mt)
            af[mt] = *(const short8*)&As[(wm + mt * 16 + l16) * 32 + quad * 8];
        #pragma unroll
        for (int nt = 0; nt < 4; ++nt)
            bfr[nt] = *(const short8*)&Bs[(wn + nt * 16 + l16) * 32 + quad * 8];
        #pragma unroll
        for (int mt = 0; mt < 4; ++mt)
            #pragma unroll
            for (int nt = 0; nt < 4; ++nt)
                acc[mt][nt] = __builtin_amdgcn_mfma_f32_16x16x32_bf16(
                    af[mt], bfr[nt], acc[mt][nt], 0, 0, 0);
        __syncthreads();
    }

    #pragma unroll
    for (int mt = 0; mt < 4; ++mt) {
        #pragma unroll
        for (int j = 0; j < 4; ++j) {
            const int row = bm0 + wm + mt * 16 + quad * 4 + j;
            if (row >= M) continue;
            #pragma unroll
            for (int nt = 0; nt < 4; ++nt) {
                const int col = bn0 + wn + nt * 16 + l16;
                C[(size_t)row * Nc + col] = acc[mt][nt][j] + bias[col];
            }
        }
    }
}

__global__ __launch_bounds__(256) void gemm_out_kernel(
    const ushort_t* __restrict__ mid, const ushort_t* __restrict__ Tout,
    const float* __restrict__ b_out, float* __restrict__ out)
{
    __shared__ ushort_t As[128 * 32];
    __shared__ ushort_t Bs[128 * 32];
    gemm_tile_core(mid, Tout, b_out, out, M_TOT, 256,
                   blockIdx.x * 128, blockIdx.y * 128, 256, As, Bs);
}

// =====================================================================
// Sampling kernel v10: consumer-indexed handoff.
//  Phase 1 stores, per sample, FOUR pre-selected {base, weight} pairs
//  (corner offset +64 pre-added into base):
//    slot j=0: {B0,    wl0}   j=1: {B0+64, wr0}
//    slot j=2: {B1,    wl1}   j=3: {B1+64, wr1}
//  Phase-2 lane (hg, rowr, corner, c4) reads exactly ONE int2 per
//  sample at slot hg*66 + t*4 + rowr*2 + corner (stride-66 padding:
//  16B-aligned int4 writes, heads shifted 4 banks apart) -- compile-
//  time immediate ds offsets, ZERO cndmask selects, one v_add for the
//  gather voffset.  Memory transactions identical to v9 (same
//  addresses, same zeroed-pad overread-with-weight-0 safety).
// =====================================================================
#define ACC8(W, g) { \
    const __half2 h0 = *(const __half2*)&(g).x; \
    const __half2 h1 = *(const __half2*)&(g).y; \
    const __half2 h2 = *(const __half2*)&(g).z; \
    const __half2 h3 = *(const __half2*)&(g).w; \
    a0 = fmaf(W, __low2float(h0),  a0);  a1 = fmaf(W, __high2float(h0), a1); \
    a2 = fmaf(W, __low2float(h1),  a2);  a3 = fmaf(W, __high2float(h1), a3); \
    a4 = fmaf(W, __low2float(h2),  a4);  a5 = fmaf(W, __high2float(h2), a5); \
    a6 = fmaf(W, __low2float(h3),  a6);  a7 = fmaf(W, __high2float(h3), a7); }

__global__ __launch_bounds__(256, 8) void msda_sample_kernel(
    const ushort_t* __restrict__ vproj, const ushort_t* __restrict__ offh,
    const float* __restrict__ p, ushort_t* __restrict__ mid)
{
    // [wave][head*66 + sample*4 + (rowr*2|corner)] ; 66 = 64 + 2 pad
    __shared__ __align__(16) int2 s_pair[4][264];

    const int tid = threadIdx.x;
    const int wv  = tid >> 6;            // wave id 0..3
    const int l   = tid & 63;
    const int idx = blockIdx.x;
    const int b8  = idx & 7;             // XCD id (round-robin assumption)
    const int hh  = b8 >> 2;             // head half: XCD 0-3 -> 0, 4-7 -> 1
    const int qg  = (idx >> 3) * 4 + (b8 & 3);
    const int nq  = qg * 4 + wv;
    const int nb  = (nq >= QN) ? 1 : 0;

    // ---- phase 1: lane = sample (h4 = l>>4, lvl = (l>>2)&3, pt = l&3)
    const size_t orow = (size_t)nq * 384;
    const __half2 o2 = *(const __half2*)&offh[orow + hh * 128 + 2 * l];
    const float2  of = __half22float2(o2);
    const float   lg = __half2float(
        *(const __half*)&offh[orow + 256 + hh * 64 + l]);
    const int     lvl = (l >> 2) & 3;
    const float2  pl  = *(const float2*)&p[(size_t)nq * 8 + lvl * 2];

    // softmax over 16-lane head groups
    float mx = lg;
    #pragma unroll
    for (int m = 8; m; m >>= 1) mx = fmaxf(mx, __shfl_xor(mx, m));
    const float e = __expf(lg - mx);
    float ss = e;
    #pragma unroll
    for (int m = 8; m; m >>= 1) ss += __shfl_xor(ss, m);
    const float wt = e * __builtin_amdgcn_rcpf(ss);

    const int   Wl = 96 >> lvl;                     // H == W per level
    const float fW = (float)Wl;
    const int   st = 12288 - (12288 >> (2 * lvl));  // level start pixel
    const int   h4 = l >> 4;
    const int   h  = hh * 4 + h4;                   // global head

    {
        const float x  = fmaf(pl.x, fW, of.x) - 0.5f;
        const float y  = fmaf(pl.y, fW, of.y) - 0.5f;
        const float xf = floorf(x), yf = floorf(y);
        const float dx = x - xf,    dy = y - yf;
        const int   x0 = (int)xf,   y0 = (int)yf;
        const bool vxl = (unsigned)x0       < (unsigned)Wl;
        const bool vxr = (unsigned)(x0 + 1) < (unsigned)Wl;
        const bool vy0 = (unsigned)y0       < (unsigned)Wl;
        const bool vy1 = (unsigned)(y0 + 1) < (unsigned)Wl;

        const float wxl = vxl ? (1.0f - dx) : (vxr ? dx : 0.0f);
        const float wxr = (vxl && vxr) ? dx : 0.0f;
        const int   xb  = vxl ? x0 : 0;

        const float wy0f = wt * (1.0f - dy), wy1f = wt * dy;
        const float w_l0 = vy0 ? wxl * wy0f : 0.0f;
        const float w_r0 = vy0 ? wxr * wy0f : 0.0f;
        const float w_l1 = vy1 ? wxl * wy1f : 0.0f;
        const float w_r1 = vy1 ? wxr * wy1f : 0.0f;

        int yc0 = y0;     if (yc0 < 0) yc0 = 0; if (yc0 > Wl - 1) yc0 = Wl - 1;
        int yc1 = y0 + 1; if (yc1 < 0) yc1 = 0; if (yc1 > Wl - 1) yc1 = Wl - 1;

        const int rowb = h * M_TOT + nb * HW_TOT + st + xb;
        const int B0 = (rowb + yc0 * Wl) << 6;  // byte base, valid pixel
        const int B1 = (rowb + yc1 * Wl) << 6;  // (pair's right chunk of the
                                                //  final pixel reads the
                                                //  zeroed pad with w = 0)
        const int slot = h4 * 66 + (l & 15) * 4;
        *(int4*)&s_pair[wv][slot]     = (int4){B0, __float_as_int(w_l0),
                                               B0 + 64, __float_as_int(w_r0)};
        *(int4*)&s_pair[wv][slot + 2] = (int4){B1, __float_as_int(w_l1),
                                               B1 + 64, __float_as_int(w_r1)};
    }

    // wave-local LDS handoff: DS ops are in-order per wave; drain lgkm
    // and fence the compiler.  No s_barrier -- waves are independent.
    __builtin_amdgcn_wave_barrier();
    asm volatile("s_waitcnt lgkmcnt(0)" ::: "memory");
    __builtin_amdgcn_wave_barrier();

    // ---- phase 2: lane = (head hg, row rowr, corner, ch-quad c4)
    const int hg     = l >> 4;           // head within half
    const int rowr   = (l >> 3) & 1;
    const int corner = (l >> 2) & 1;
    const int c4x16  = (l & 3) * 16;     // byte offset within 64B chunk
    const char* __restrict__ vb = (const char*)vproj;
    const int2* __restrict__ rp = &s_pair[wv][hg * 66 + rowr * 2 + corner];

    float a0 = 0.f, a1 = 0.f, a2 = 0.f, a3 = 0.f;
    float a4 = 0.f, a5 = 0.f, a6 = 0.f, a7 = 0.f;

    #pragma unroll 8
    for (int t = 0; t < 16; ++t) {
        const int2 rd = rp[t * 4];          // {base, weight} -- imm offset
        const float w = __int_as_float(rd.y);
        const uint4 g = *(const uint4*)(vb + (unsigned)(rd.x + c4x16));
        ACC8(w, g);
    }

    // fold corners (bit2) then rows (bit3)
    a0 += __shfl_xor(a0, 4);  a1 += __shfl_xor(a1, 4);
    a2 += __shfl_xor(a2, 4);  a3 += __shfl_xor(a3, 4);
    a4 += __shfl_xor(a4, 4);  a5 += __shfl_xor(a5, 4);
    a6 += __shfl_xor(a6, 4);  a7 += __shfl_xor(a7, 4);
    a0 += __shfl_xor(a0, 8);  a1 += __shfl_xor(a1, 8);
    a2 += __shfl_xor(a2, 8);  a3 += __shfl_xor(a3, 8);
    a4 += __shfl_xor(a4, 8);  a5 += __shfl_xor(a5, 8);
    a6 += __shfl_xor(a6, 8);  a7 += __shfl_xor(a7, 8);

    if ((l & 12) == 0) {                 // 4 writer lanes per head
        ushort_t mv[8] = {f2bf(a0), f2bf(a1), f2bf(a2), f2bf(a3),
                          f2bf(a4), f2bf(a5), f2bf(a6), f2bf(a7)};
        const int col = (hh * 4 + hg) * 32 + (l & 3) * 8;
        *(uint4*)&mid[(size_t)nq * 256 + col] = *(uint4*)mv;
    }
}

// =====================================================================
extern "C" void kernel_launch(void* const* d_in, const int* in_sizes, int n_in,
                              void* d_out, int out_size, void* d_ws, size_t ws_size,
                              hipStream_t stream)
{
    const float* q      = (const float*)d_in[0];
    const float* p      = (const float*)d_in[1];
    const float* v      = (const float*)d_in[2];
    const float* W_off  = (const float*)d_in[3];
    const float* b_off  = (const float*)d_in[4];
    const float* W_attn = (const float*)d_in[5];
    const float* b_attn = (const float*)d_in[6];
    const float* W_in   = (const float*)d_in[7];
    const float* b_in   = (const float*)d_in[8];
    const float* W_out  = (const float*)d_in[9];
    const float* b_out  = (const float*)d_in[10];
    float* out = (float*)d_out;

    const int M = M_TOT;                            // 24480

    // workspace layout.  vproj (fp16 head-major) is followed by a 128B
    // ZEROED pad (sampler overread safety; fp16 zero = 0x0000).
    ushort_t* vproj  = (ushort_t*)d_ws;                          // M*256 fp16 (head-major)
    ushort_t* vpad   = vproj + (size_t)M * 256;                  // 64 ushort = 128B zero pad
    ushort_t* offh   = vpad + 64;                                // M*384 fp16
    ushort_t* mid    = offh + (size_t)M * 384;                   // M*256 bf16
    ushort_t* Tin    = mid + (size_t)M * 256;
    ushort_t* Tcomb  = Tin + 256 * 256;
    ushort_t* Tout   = Tcomb + 384 * 256;
    float*    bcomb  = (float*)(Tout + 256 * 256);

    // 0) weight transposes/fusion + pad zero (small)
    prep_weights_kernel<<<dim3(384), 256, 0, stream>>>(
        W_in, W_off, W_attn, W_out, b_off, b_attn,
        Tin, Tcomb, Tout, bcomb, (int*)vpad);

    // 1) fused convert+projection GEMMs (reads RAW fp32 v/q)
    gemm_proj_kernel<<<dim3(192, 3), 256, 0, stream>>>(
        v, q, Tin, Tcomb, b_in, bcomb, vproj, offh);
    // 2) softmax + bilinear sampling -> bf16 mid (consumer-indexed LDS)
    msda_sample_kernel<<<dim3(12240), 256, 0, stream>>>(vproj, offh, p, mid);
    // 3) out = mid @ W_out + b_out
    gemm_out_kernel<<<dim3(192, 2), 256, 0, stream>>>(mid, Tout, b_out, out);
}

// Round 10
// 183.452 us; speedup vs baseline: 1.0350x; 1.0350x over previous
//
#include <hip/hip_runtime.h>
#include <hip/hip_bf16.h>
#include <hip/hip_fp16.h>
#include <math.h>

// ---- problem constants (structural, from the reference) ----
#define NB      2
#define QN      12240
#define HW_TOT  12240
#define DIMS    256
#define HEADS   8
#define CH      32
#define LEVELS  4
#define POINTS  4
#define M_TOT   (NB * QN)        // 24480

typedef unsigned short ushort_t;
typedef __attribute__((ext_vector_type(8))) short short8;
typedef __attribute__((ext_vector_type(4))) float floatx4;

__device__ __forceinline__ ushort_t f2bf(float f) {
    __hip_bfloat16 h = __float2bfloat16(f);
    return *reinterpret_cast<ushort_t*>(&h);
}
__device__ __forceinline__ ushort_t f2h(float f) {
    __half h = __float2half(f);
    return *reinterpret_cast<ushort_t*>(&h);
}

#define GLOAD16(gp, lp) __builtin_amdgcn_global_load_lds( \
    (const __attribute__((address_space(1))) void*)(gp),  \
    (__attribute__((address_space(3))) void*)(lp), 16, 0, 0)

// =====================================================================
// Weights -> transposed bf16 (small, 384 blocks): Tin/Tout (gi<65536),
// Tcomb [384][256], combined bias, and the 128B zero pad after vproj.
// =====================================================================
__global__ __launch_bounds__(256) void prep_weights_kernel(
    const float* __restrict__ W_in, const float* __restrict__ W_off,
    const float* __restrict__ W_attn, const float* __restrict__ W_out,
    const float* __restrict__ b_off, const float* __restrict__ b_attn,
    ushort_t* __restrict__ Tin, ushort_t* __restrict__ Tcomb,
    ushort_t* __restrict__ Tout, float* __restrict__ bcomb,
    int* __restrict__ vpad)
{
    const int gi = blockIdx.x * 256 + threadIdx.x;   // grid = 384 blocks
    if (gi < 32)  vpad[gi] = 0;                      // 128B zero pad
    if (gi < 384) bcomb[gi] = (gi < 256) ? b_off[gi] : b_attn[gi - 256];
    const int k = gi & 255;                          // coalesced along k
    const int n = gi >> 8;
    if (gi < 65536) {
        Tin[n * 256 + k]  = f2bf(W_in[k * 256 + n]);
        Tout[n * 256 + k] = f2bf(W_out[k * 256 + n]);
    }
    const float val = (n < 256) ? W_off[k * 256 + n]
                                : W_attn[k * 128 + (n - 256)];
    Tcomb[n * 256 + k] = f2bf(val);
}

// =====================================================================
// Fused-convert GEMM tile (R6 single-buffer structure, unchanged).
// CMODE: 1 = FP16 HEAD-MAJOR vproj ((h*M+row)*32+ch), 2 = fp16 row-major.
// =====================================================================
template<int CMODE, bool DUAL>
__device__ __forceinline__ void gemm_fused_tile(
    const float* __restrict__ A32, const ushort_t* __restrict__ BT,
    const float* __restrict__ bias, void* __restrict__ C,
    int M, int Nc, int bm0, int bn0a, int bn0b,
    ushort_t* As, ushort_t* Bs0, ushort_t* Bs1)
{
    const int tid  = threadIdx.x;
    const int wave = tid >> 6;
    const int lane = tid & 63;
    const int quad = lane >> 4;
    const int l16  = lane & 15;
    const int wm   = (wave >> 1) * 64;
    const int wn   = (wave & 1) * 64;

    const int off0 = tid * 16;            // LDS byte offset (linear)
    const int row0 = off0 >> 6;           // 0..63 (64B = 32 bf16/row)
    const int kc0  = (off0 & 63) >> 1;    // element k-offset: 0/8/16/24

    int ar0 = bm0 + row0;      if (ar0 > M - 1) ar0 = M - 1;
    int ar1 = bm0 + row0 + 64; if (ar1 > M - 1) ar1 = M - 1;

    const float*    gA0  = A32 + (size_t)ar0 * 256 + kc0;
    const float*    gA1  = A32 + (size_t)ar1 * 256 + kc0;
    const ushort_t* gb0a = BT + (size_t)(bn0a + row0) * 256 + kc0;
    const ushort_t* gb1a = BT + (size_t)(bn0a + row0 + 64) * 256 + kc0;
    const ushort_t* gb0b = BT + (size_t)(bn0b + row0) * 256 + kc0;
    const ushort_t* gb1b = BT + (size_t)(bn0b + row0 + 64) * 256 + kc0;

    ushort_t* lB0a = Bs0 + wave * 512;
    ushort_t* lB1a = Bs0 + wave * 512 + 2048;
    ushort_t* lB0b = Bs1 + wave * 512;
    ushort_t* lB1b = Bs1 + wave * 512 + 2048;

    floatx4 acc0[4][4], acc1[4][4];
    #pragma unroll
    for (int i = 0; i < 4; ++i)
        #pragma unroll
        for (int j = 0; j < 4; ++j) {
            acc0[i][j] = (floatx4){0.f, 0.f, 0.f, 0.f};
            if (DUAL) acc1[i][j] = (floatx4){0.f, 0.f, 0.f, 0.f};
        }

    for (int kk = 0; kk < 256; kk += 32) {
        GLOAD16(gb0a + kk, lB0a);
        GLOAD16(gb1a + kk, lB1a);
        if (DUAL) {
            GLOAD16(gb0b + kk, lB0b);
            GLOAD16(gb1b + kk, lB1b);
        }
        // A: fp32 -> bf16 reg-staged (each thread: 2 rows x 8 elems)
        {
            const float4 a0 = *(const float4*)(gA0 + kk);
            const float4 a1 = *(const float4*)(gA0 + kk + 4);
            const float4 b0 = *(const float4*)(gA1 + kk);
            const float4 b1 = *(const float4*)(gA1 + kk + 4);
            ushort_t t0[8] = {f2bf(a0.x), f2bf(a0.y), f2bf(a0.z), f2bf(a0.w),
                              f2bf(a1.x), f2bf(a1.y), f2bf(a1.z), f2bf(a1.w)};
            ushort_t t1[8] = {f2bf(b0.x), f2bf(b0.y), f2bf(b0.z), f2bf(b0.w),
                              f2bf(b1.x), f2bf(b1.y), f2bf(b1.z), f2bf(b1.w)};
            *(int4*)&As[tid * 8]        = *(int4*)t0;
            *(int4*)&As[tid * 8 + 2048] = *(int4*)t1;
        }
        __syncthreads();

        short8 af[4], bfa[4], bfb[4];
        #pragma unroll
        for (int mt = 0; mt < 4; ++mt)
            af[mt] = *(const short8*)&As[(wm + mt * 16 + l16) * 32 + quad * 8];
        #pragma unroll
        for (int nt = 0; nt < 4; ++nt) {
            bfa[nt] = *(const short8*)&Bs0[(wn + nt * 16 + l16) * 32 + quad * 8];
            if (DUAL)
                bfb[nt] = *(const short8*)&Bs1[(wn + nt * 16 + l16) * 32 + quad * 8];
        }
        #pragma unroll
        for (int mt = 0; mt < 4; ++mt)
            #pragma unroll
            for (int nt = 0; nt < 4; ++nt) {
                acc0[mt][nt] = __builtin_amdgcn_mfma_f32_16x16x32_bf16(
                    af[mt], bfa[nt], acc0[mt][nt], 0, 0, 0);
                if (DUAL)
                    acc1[mt][nt] = __builtin_amdgcn_mfma_f32_16x16x32_bf16(
                        af[mt], bfb[nt], acc1[mt][nt], 0, 0, 0);
            }
        __syncthreads();
    }

    #pragma unroll
    for (int mt = 0; mt < 4; ++mt) {
        #pragma unroll
        for (int j = 0; j < 4; ++j) {
            const int row = bm0 + wm + mt * 16 + quad * 4 + j;
            if (row >= M) continue;
            #pragma unroll
            for (int nt = 0; nt < 4; ++nt) {
                {
                    const int col = bn0a + wn + nt * 16 + l16;
                    const float val = acc0[mt][nt][j] + bias[col];
                    if (CMODE == 1) {
                        const size_t idx = (((size_t)(col >> 5) * M + row) << 5) + (col & 31);
                        ((ushort_t*)C)[idx] = f2h(val);          // fp16 vproj
                    } else {
                        ((ushort_t*)C)[(size_t)row * Nc + col] = f2h(val);
                    }
                }
                if (DUAL) {
                    const int col = bn0b + wn + nt * 16 + l16;
                    const float val = acc1[mt][nt][j] + bias[col];
                    if (CMODE == 1) {
                        const size_t idx = (((size_t)(col >> 5) * M + row) << 5) + (col & 31);
                        ((ushort_t*)C)[idx] = f2h(val);          // fp16 vproj
                    } else {
                        ((ushort_t*)C)[(size_t)row * Nc + col] = f2h(val);
                    }
                }
            }
        }
    }
}

__global__ __launch_bounds__(256) void gemm_proj_kernel(
    const float* __restrict__ v, const float* __restrict__ q,
    const ushort_t* __restrict__ Tin, const ushort_t* __restrict__ Tcomb,
    const float* __restrict__ b_in, const float* __restrict__ bcomb,
    ushort_t* __restrict__ vproj, ushort_t* __restrict__ offh)
{
    __shared__ ushort_t As [128 * 32];
    __shared__ ushort_t Bs0[128 * 32];
    __shared__ ushort_t Bs1[128 * 32];
    const int bm0 = blockIdx.x * 128;
    const int y = blockIdx.y;
    if (y == 0)       // vproj = v @ W_in (fp16 head-major), both col-tiles
        gemm_fused_tile<1, true >(v, Tin,   b_in,  vproj, M_TOT, 256, bm0, 0, 128, As, Bs0, Bs1);
    else if (y == 1)  // offh cols 0-255 = q @ Tcomb (fp16)
        gemm_fused_tile<2, true >(q, Tcomb, bcomb, offh,  M_TOT, 384, bm0, 0, 128, As, Bs0, Bs1);
    else              // offh cols 256-383
        gemm_fused_tile<2, false>(q, Tcomb, bcomb, offh,  M_TOT, 384, bm0, 256, 0, As, Bs0, Bs1);
}

// =====================================================================
// Output GEMM, BK=64: 4 K-steps instead of 8 -> HALF the per-step
// vmcnt(0)+barrier drains, 2x MFMA (32) + ds_read (16) per drain.
// Single-buffered 32 KB LDS (5 blocks/CU LDS-bound; VGPR ~120 keeps
// 4 waves/SIMD) -- unlike R7's dbuf, occupancy is preserved.
// Staging: thread tid covers 4x16B chunks at byte off tid*16 + j*4096;
// row = tid/8 + j*32, k-elem = (tid&7)*8 (j-independent).
// =====================================================================
__global__ __launch_bounds__(256) void gemm_out_kernel(
    const ushort_t* __restrict__ mid, const ushort_t* __restrict__ Tout,
    const float* __restrict__ b_out, float* __restrict__ out)
{
    __shared__ ushort_t As[128 * 64];   // 16 KB
    __shared__ ushort_t Bs[128 * 64];   // 16 KB

    const int tid  = threadIdx.x;
    const int wave = tid >> 6;
    const int lane = tid & 63;
    const int quad = lane >> 4;
    const int l16  = lane & 15;
    const int wm   = (wave >> 1) * 64;
    const int wn   = (wave & 1) * 64;
    const int bm0  = blockIdx.x * 128;
    const int bn0  = blockIdx.y * 128;
    const int M    = M_TOT;

    const int rowt = tid >> 3;          // 0..31 (row within 32-row band)
    const int kc   = (tid & 7) * 8;     // k-element offset 0..56

    // global row pointers per chunk j (row = rowt + j*32)
    const ushort_t* gA[4];
    const ushort_t* gB[4];
    #pragma unroll
    for (int j = 0; j < 4; ++j) {
        int ar = bm0 + rowt + j * 32; if (ar > M - 1) ar = M - 1;
        gA[j] = mid  + (size_t)ar * 256 + kc;
        gB[j] = Tout + (size_t)(bn0 + rowt + j * 32) * 256 + kc;
    }

    floatx4 acc[4][4];
    #pragma unroll
    for (int i = 0; i < 4; ++i)
        #pragma unroll
        for (int j = 0; j < 4; ++j)
            acc[i][j] = (floatx4){0.f, 0.f, 0.f, 0.f};

    for (int kk = 0; kk < 256; kk += 64) {
        #pragma unroll
        for (int j = 0; j < 4; ++j) {
            GLOAD16(gA[j] + kk, As + j * 2048 + wave * 512);
            GLOAD16(gB[j] + kk, Bs + j * 2048 + wave * 512);
        }
        __syncthreads();

        #pragma unroll
        for (int s = 0; s < 2; ++s) {
            short8 af[4], bfr[4];
            #pragma unroll
            for (int mt = 0; mt < 4; ++mt)
                af[mt] = *(const short8*)&As[(wm + mt * 16 + l16) * 64 + s * 32 + quad * 8];
            #pragma unroll
            for (int nt = 0; nt < 4; ++nt)
                bfr[nt] = *(const short8*)&Bs[(wn + nt * 16 + l16) * 64 + s * 32 + quad * 8];
            #pragma unroll
            for (int mt = 0; mt < 4; ++mt)
                #pragma unroll
                for (int nt = 0; nt < 4; ++nt)
                    acc[mt][nt] = __builtin_amdgcn_mfma_f32_16x16x32_bf16(
                        af[mt], bfr[nt], acc[mt][nt], 0, 0, 0);
        }
        __syncthreads();
    }

    #pragma unroll
    for (int mt = 0; mt < 4; ++mt) {
        #pragma unroll
        for (int j = 0; j < 4; ++j) {
            const int row = bm0 + wm + mt * 16 + quad * 4 + j;
            if (row >= M) continue;
            #pragma unroll
            for (int nt = 0; nt < 4; ++nt) {
                const int col = bn0 + wn + nt * 16 + l16;
                out[(size_t)row * 256 + col] = acc[mt][nt][j] + b_out[col];
            }
        }
    }
}

// =====================================================================
// Sampling kernel v9 (REVERTED to R8 exact -- R9's consumer-indexed
// handoff had a 4-way LDS WRITE conflict, 783K conflicts, 43.9->51.4).
// Head-split + XCD locality + fp16 offlog + fp16 vproj fma_mix decode;
// stride-17 int4/int2 handoff (measured 0 conflicts).
// =====================================================================
#define ACC8(W, g) { \
    const __half2 h0 = *(const __half2*)&(g).x; \
    const __half2 h1 = *(const __half2*)&(g).y; \
    const __half2 h2 = *(const __half2*)&(g).z; \
    const __half2 h3 = *(const __half2*)&(g).w; \
    a0 = fmaf(W, __low2float(h0),  a0);  a1 = fmaf(W, __high2float(h0), a1); \
    a2 = fmaf(W, __low2float(h1),  a2);  a3 = fmaf(W, __high2float(h1), a3); \
    a4 = fmaf(W, __low2float(h2),  a4);  a5 = fmaf(W, __high2float(h2), a5); \
    a6 = fmaf(W, __low2float(h3),  a6);  a7 = fmaf(W, __high2float(h3), a7); }

__global__ __launch_bounds__(256, 8) void msda_sample_kernel(
    const ushort_t* __restrict__ vproj, const ushort_t* __restrict__ offh,
    const float* __restrict__ p, ushort_t* __restrict__ mid)
{
    __shared__ int4 s_main[4][68];       // [wave][h4*17 + s]
    __shared__ int2 s_aux[4][68];

    const int tid = threadIdx.x;
    const int wv  = tid >> 6;            // wave id 0..3
    const int l   = tid & 63;
    const int idx = blockIdx.x;
    const int b8  = idx & 7;             // XCD id (round-robin assumption)
    const int hh  = b8 >> 2;             // head half: XCD 0-3 -> 0, 4-7 -> 1
    const int qg  = (idx >> 3) * 4 + (b8 & 3);
    const int nq  = qg * 4 + wv;
    const int nb  = (nq >= QN) ? 1 : 0;

    // ---- phase 1: lane = sample (h4 = l>>4, lvl = (l>>2)&3, pt = l&3)
    const size_t orow = (size_t)nq * 384;
    const __half2 o2 = *(const __half2*)&offh[orow + hh * 128 + 2 * l];
    const float2  of = __half22float2(o2);
    const float   lg = __half2float(
        *(const __half*)&offh[orow + 256 + hh * 64 + l]);
    const int     lvl = (l >> 2) & 3;
    const float2  pl  = *(const float2*)&p[(size_t)nq * 8 + lvl * 2];

    // softmax over 16-lane head groups
    float mx = lg;
    #pragma unroll
    for (int m = 8; m; m >>= 1) mx = fmaxf(mx, __shfl_xor(mx, m));
    const float e = __expf(lg - mx);
    float ss = e;
    #pragma unroll
    for (int m = 8; m; m >>= 1) ss += __shfl_xor(ss, m);
    const float wt = e * __builtin_amdgcn_rcpf(ss);

    const int   Wl = 96 >> lvl;                     // H == W per level
    const float fW = (float)Wl;
    const int   st = 12288 - (12288 >> (2 * lvl));  // level start pixel
    const int   h4 = l >> 4;
    const int   h  = hh * 4 + h4;                   // global head

    {
        const float x  = fmaf(pl.x, fW, of.x) - 0.5f;
        const float y  = fmaf(pl.y, fW, of.y) - 0.5f;
        const float xf = floorf(x), yf = floorf(y);
        const float dx = x - xf,    dy = y - yf;
        const int   x0 = (int)xf,   y0 = (int)yf;
        const bool vxl = (unsigned)x0       < (unsigned)Wl;
        const bool vxr = (unsigned)(x0 + 1) < (unsigned)Wl;
        const bool vy0 = (unsigned)y0       < (unsigned)Wl;
        const bool vy1 = (unsigned)(y0 + 1) < (unsigned)Wl;

        const float wxl = vxl ? (1.0f - dx) : (vxr ? dx : 0.0f);
        const float wxr = (vxl && vxr) ? dx : 0.0f;
        const int   xb  = vxl ? x0 : 0;

        const float wy0f = wt * (1.0f - dy), wy1f = wt * dy;
        const float w_l0 = vy0 ? wxl * wy0f : 0.0f;
        const float w_r0 = vy0 ? wxr * wy0f : 0.0f;
        const float w_l1 = vy1 ? wxl * wy1f : 0.0f;
        const float w_r1 = vy1 ? wxr * wy1f : 0.0f;

        int yc0 = y0;     if (yc0 < 0) yc0 = 0; if (yc0 > Wl - 1) yc0 = Wl - 1;
        int yc1 = y0 + 1; if (yc1 < 0) yc1 = 0; if (yc1 > Wl - 1) yc1 = Wl - 1;

        const int rowb = h * M_TOT + nb * HW_TOT + st + xb;
        const int lin0 = rowb + yc0 * Wl;   // valid pixel-head index
        const int lin1 = rowb + yc1 * Wl;   // (final pixel's right chunk
                                            //  reads the zeroed pad, w=0)
        const int e17 = h4 * 17 + (l & 15);
        s_main[wv][e17] = (int4){lin0 << 6, __float_as_int(w_l0),
                                 __float_as_int(w_r0), lin1 << 6};
        s_aux[wv][e17]  = (int2){__float_as_int(w_l1), __float_as_int(w_r1)};
    }

    // wave-local LDS handoff: DS ops are in-order per wave; drain lgkm
    // and fence the compiler.  No s_barrier -- waves are independent.
    __builtin_amdgcn_wave_barrier();
    asm volatile("s_waitcnt lgkmcnt(0)" ::: "memory");
    __builtin_amdgcn_wave_barrier();

    // ---- phase 2: lane = (head hg, row r, corner, ch-quad)
    const int hg     = l >> 4;           // head within half
    const int rowr   = (l >> 3) & 1;
    const int corner = (l >> 2) & 1;
    const int c16    = (l & 7) * 16;     // byte offset within 128B pair
    const char* __restrict__ vb = (const char*)vproj;

    float a0 = 0.f, a1 = 0.f, a2 = 0.f, a3 = 0.f;
    float a4 = 0.f, a5 = 0.f, a6 = 0.f, a7 = 0.f;

    #pragma unroll 4
    for (int t = 0; t < 16; ++t) {
        const int  e17 = hg * 17 + t;
        const int4 c   = s_main[wv][e17];   // {b0, wl0, wr0, b1}
        const int2 cb  = s_aux[wv][e17];    // {wl1, wr1}
        const int  base = rowr ? c.w : c.x;
        const float wl  = rowr ? __int_as_float(cb.x) : __int_as_float(c.y);
        const float wr  = rowr ? __int_as_float(cb.y) : __int_as_float(c.z);
        const float w   = corner ? wr : wl;
        const uint4 g   = *(const uint4*)(vb + (unsigned)(base + c16));
        ACC8(w, g);
    }

    // fold corners (bit2) then rows (bit3)
    a0 += __shfl_xor(a0, 4);  a1 += __shfl_xor(a1, 4);
    a2 += __shfl_xor(a2, 4);  a3 += __shfl_xor(a3, 4);
    a4 += __shfl_xor(a4, 4);  a5 += __shfl_xor(a5, 4);
    a6 += __shfl_xor(a6, 4);  a7 += __shfl_xor(a7, 4);
    a0 += __shfl_xor(a0, 8);  a1 += __shfl_xor(a1, 8);
    a2 += __shfl_xor(a2, 8);  a3 += __shfl_xor(a3, 8);
    a4 += __shfl_xor(a4, 8);  a5 += __shfl_xor(a5, 8);
    a6 += __shfl_xor(a6, 8);  a7 += __shfl_xor(a7, 8);

    if ((l & 12) == 0) {                 // 4 writer lanes per head
        ushort_t mv[8] = {f2bf(a0), f2bf(a1), f2bf(a2), f2bf(a3),
                          f2bf(a4), f2bf(a5), f2bf(a6), f2bf(a7)};
        const int col = (hh * 4 + hg) * 32 + (l & 3) * 8;
        *(uint4*)&mid[(size_t)nq * 256 + col] = *(uint4*)mv;
    }
}

// =====================================================================
extern "C" void kernel_launch(void* const* d_in, const int* in_sizes, int n_in,
                              void* d_out, int out_size, void* d_ws, size_t ws_size,
                              hipStream_t stream)
{
    const float* q      = (const float*)d_in[0];
    const float* p      = (const float*)d_in[1];
    const float* v      = (const float*)d_in[2];
    const float* W_off  = (const float*)d_in[3];
    const float* b_off  = (const float*)d_in[4];
    const float* W_attn = (const float*)d_in[5];
    const float* b_attn = (const float*)d_in[6];
    const float* W_in   = (const float*)d_in[7];
    const float* b_in   = (const float*)d_in[8];
    const float* W_out  = (const float*)d_in[9];
    const float* b_out  = (const float*)d_in[10];
    float* out = (float*)d_out;

    const int M = M_TOT;                            // 24480

    // workspace layout.  vproj (fp16 head-major) is followed by a 128B
    // ZEROED pad (sampler overread safety; fp16 zero = 0x0000).
    ushort_t* vproj  = (ushort_t*)d_ws;                          // M*256 fp16 (head-major)
    ushort_t* vpad   = vproj + (size_t)M * 256;                  // 64 ushort = 128B zero pad
    ushort_t* offh   = vpad + 64;                                // M*384 fp16
    ushort_t* mid    = offh + (size_t)M * 384;                   // M*256 bf16
    ushort_t* Tin    = mid + (size_t)M * 256;
    ushort_t* Tcomb  = Tin + 256 * 256;
    ushort_t* Tout   = Tcomb + 384 * 256;
    float*    bcomb  = (float*)(Tout + 256 * 256);

    // 0) weight transposes/fusion + pad zero (small)
    prep_weights_kernel<<<dim3(384), 256, 0, stream>>>(
        W_in, W_off, W_attn, W_out, b_off, b_attn,
        Tin, Tcomb, Tout, bcomb, (int*)vpad);

    // 1) fused convert+projection GEMMs (reads RAW fp32 v/q)
    gemm_proj_kernel<<<dim3(192, 3), 256, 0, stream>>>(
        v, q, Tin, Tcomb, b_in, bcomb, vproj, offh);
    // 2) softmax + bilinear sampling -> bf16 mid (v9, reverted)
    msda_sample_kernel<<<dim3(12240), 256, 0, stream>>>(vproj, offh, p, mid);
    // 3) out = mid @ W_out + b_out (BK=64: half the barrier drains)
    gemm_out_kernel<<<dim3(192, 2), 256, 0, stream>>>(mid, Tout, b_out, out);
}

// Round 11
// 183.254 us; speedup vs baseline: 1.0361x; 1.0011x over previous
//
#include <hip/hip_runtime.h>
#include <hip/hip_bf16.h>
#include <hip/hip_fp16.h>
#include <math.h>

// ---- problem constants (structural, from the reference) ----
#define NB      2
#define QN      12240
#define HW_TOT  12240
#define DIMS    256
#define HEADS   8
#define CH      32
#define LEVELS  4
#define POINTS  4
#define M_TOT   (NB * QN)        // 24480

typedef unsigned short ushort_t;
typedef __attribute__((ext_vector_type(8))) short short8;
typedef __attribute__((ext_vector_type(4))) float floatx4;

__device__ __forceinline__ ushort_t f2bf(float f) {
    __hip_bfloat16 h = __float2bfloat16(f);
    return *reinterpret_cast<ushort_t*>(&h);
}
__device__ __forceinline__ ushort_t f2h(float f) {
    __half h = __float2half(f);
    return *reinterpret_cast<ushort_t*>(&h);
}

#define GLOAD16(gp, lp) __builtin_amdgcn_global_load_lds( \
    (const __attribute__((address_space(1))) void*)(gp),  \
    (__attribute__((address_space(3))) void*)(lp), 16, 0, 0)

// =====================================================================
// Weights -> transposed bf16 (small, 384 blocks): Tin/Tout (gi<65536),
// Tcomb [384][256], combined bias, and the 128B zero pad after vproj.
// =====================================================================
__global__ __launch_bounds__(256) void prep_weights_kernel(
    const float* __restrict__ W_in, const float* __restrict__ W_off,
    const float* __restrict__ W_attn, const float* __restrict__ W_out,
    const float* __restrict__ b_off, const float* __restrict__ b_attn,
    ushort_t* __restrict__ Tin, ushort_t* __restrict__ Tcomb,
    ushort_t* __restrict__ Tout, float* __restrict__ bcomb,
    int* __restrict__ vpad)
{
    const int gi = blockIdx.x * 256 + threadIdx.x;   // grid = 384 blocks
    if (gi < 32)  vpad[gi] = 0;                      // 128B zero pad
    if (gi < 384) bcomb[gi] = (gi < 256) ? b_off[gi] : b_attn[gi - 256];
    const int k = gi & 255;                          // coalesced along k
    const int n = gi >> 8;
    if (gi < 65536) {
        Tin[n * 256 + k]  = f2bf(W_in[k * 256 + n]);
        Tout[n * 256 + k] = f2bf(W_out[k * 256 + n]);
    }
    const float val = (n < 256) ? W_off[k * 256 + n]
                                : W_attn[k * 128 + (n - 256)];
    Tcomb[n * 256 + k] = f2bf(val);
}

// =====================================================================
// Fused-convert GEMM tile (R6 single-buffer structure, unchanged).
// CMODE: 1 = FP16 HEAD-MAJOR vproj ((h*M+row)*32+ch), 2 = fp16 row-major.
// =====================================================================
template<int CMODE, bool DUAL>
__device__ __forceinline__ void gemm_fused_tile(
    const float* __restrict__ A32, const ushort_t* __restrict__ BT,
    const float* __restrict__ bias, void* __restrict__ C,
    int M, int Nc, int bm0, int bn0a, int bn0b,
    ushort_t* As, ushort_t* Bs0, ushort_t* Bs1)
{
    const int tid  = threadIdx.x;
    const int wave = tid >> 6;
    const int lane = tid & 63;
    const int quad = lane >> 4;
    const int l16  = lane & 15;
    const int wm   = (wave >> 1) * 64;
    const int wn   = (wave & 1) * 64;

    const int off0 = tid * 16;            // LDS byte offset (linear)
    const int row0 = off0 >> 6;           // 0..63 (64B = 32 bf16/row)
    const int kc0  = (off0 & 63) >> 1;    // element k-offset: 0/8/16/24

    int ar0 = bm0 + row0;      if (ar0 > M - 1) ar0 = M - 1;
    int ar1 = bm0 + row0 + 64; if (ar1 > M - 1) ar1 = M - 1;

    const float*    gA0  = A32 + (size_t)ar0 * 256 + kc0;
    const float*    gA1  = A32 + (size_t)ar1 * 256 + kc0;
    const ushort_t* gb0a = BT + (size_t)(bn0a + row0) * 256 + kc0;
    const ushort_t* gb1a = BT + (size_t)(bn0a + row0 + 64) * 256 + kc0;
    const ushort_t* gb0b = BT + (size_t)(bn0b + row0) * 256 + kc0;
    const ushort_t* gb1b = BT + (size_t)(bn0b + row0 + 64) * 256 + kc0;

    ushort_t* lB0a = Bs0 + wave * 512;
    ushort_t* lB1a = Bs0 + wave * 512 + 2048;
    ushort_t* lB0b = Bs1 + wave * 512;
    ushort_t* lB1b = Bs1 + wave * 512 + 2048;

    floatx4 acc0[4][4], acc1[4][4];
    #pragma unroll
    for (int i = 0; i < 4; ++i)
        #pragma unroll
        for (int j = 0; j < 4; ++j) {
            acc0[i][j] = (floatx4){0.f, 0.f, 0.f, 0.f};
            if (DUAL) acc1[i][j] = (floatx4){0.f, 0.f, 0.f, 0.f};
        }

    for (int kk = 0; kk < 256; kk += 32) {
        GLOAD16(gb0a + kk, lB0a);
        GLOAD16(gb1a + kk, lB1a);
        if (DUAL) {
            GLOAD16(gb0b + kk, lB0b);
            GLOAD16(gb1b + kk, lB1b);
        }
        // A: fp32 -> bf16 reg-staged (each thread: 2 rows x 8 elems)
        {
            const float4 a0 = *(const float4*)(gA0 + kk);
            const float4 a1 = *(const float4*)(gA0 + kk + 4);
            const float4 b0 = *(const float4*)(gA1 + kk);
            const float4 b1 = *(const float4*)(gA1 + kk + 4);
            ushort_t t0[8] = {f2bf(a0.x), f2bf(a0.y), f2bf(a0.z), f2bf(a0.w),
                              f2bf(a1.x), f2bf(a1.y), f2bf(a1.z), f2bf(a1.w)};
            ushort_t t1[8] = {f2bf(b0.x), f2bf(b0.y), f2bf(b0.z), f2bf(b0.w),
                              f2bf(b1.x), f2bf(b1.y), f2bf(b1.z), f2bf(b1.w)};
            *(int4*)&As[tid * 8]        = *(int4*)t0;
            *(int4*)&As[tid * 8 + 2048] = *(int4*)t1;
        }
        __syncthreads();

        short8 af[4], bfa[4], bfb[4];
        #pragma unroll
        for (int mt = 0; mt < 4; ++mt)
            af[mt] = *(const short8*)&As[(wm + mt * 16 + l16) * 32 + quad * 8];
        #pragma unroll
        for (int nt = 0; nt < 4; ++nt) {
            bfa[nt] = *(const short8*)&Bs0[(wn + nt * 16 + l16) * 32 + quad * 8];
            if (DUAL)
                bfb[nt] = *(const short8*)&Bs1[(wn + nt * 16 + l16) * 32 + quad * 8];
        }
        #pragma unroll
        for (int mt = 0; mt < 4; ++mt)
            #pragma unroll
            for (int nt = 0; nt < 4; ++nt) {
                acc0[mt][nt] = __builtin_amdgcn_mfma_f32_16x16x32_bf16(
                    af[mt], bfa[nt], acc0[mt][nt], 0, 0, 0);
                if (DUAL)
                    acc1[mt][nt] = __builtin_amdgcn_mfma_f32_16x16x32_bf16(
                        af[mt], bfb[nt], acc1[mt][nt], 0, 0, 0);
            }
        __syncthreads();
    }

    #pragma unroll
    for (int mt = 0; mt < 4; ++mt) {
        #pragma unroll
        for (int j = 0; j < 4; ++j) {
            const int row = bm0 + wm + mt * 16 + quad * 4 + j;
            if (row >= M) continue;
            #pragma unroll
            for (int nt = 0; nt < 4; ++nt) {
                {
                    const int col = bn0a + wn + nt * 16 + l16;
                    const float val = acc0[mt][nt][j] + bias[col];
                    if (CMODE == 1) {
                        const size_t idx = (((size_t)(col >> 5) * M + row) << 5) + (col & 31);
                        ((ushort_t*)C)[idx] = f2h(val);          // fp16 vproj
                    } else {
                        ((ushort_t*)C)[(size_t)row * Nc + col] = f2h(val);
                    }
                }
                if (DUAL) {
                    const int col = bn0b + wn + nt * 16 + l16;
                    const float val = acc1[mt][nt][j] + bias[col];
                    if (CMODE == 1) {
                        const size_t idx = (((size_t)(col >> 5) * M + row) << 5) + (col & 31);
                        ((ushort_t*)C)[idx] = f2h(val);          // fp16 vproj
                    } else {
                        ((ushort_t*)C)[(size_t)row * Nc + col] = f2h(val);
                    }
                }
            }
        }
    }
}

__global__ __launch_bounds__(256) void gemm_proj_kernel(
    const float* __restrict__ v, const float* __restrict__ q,
    const ushort_t* __restrict__ Tin, const ushort_t* __restrict__ Tcomb,
    const float* __restrict__ b_in, const float* __restrict__ bcomb,
    ushort_t* __restrict__ vproj, ushort_t* __restrict__ offh)
{
    __shared__ ushort_t As [128 * 32];
    __shared__ ushort_t Bs0[128 * 32];
    __shared__ ushort_t Bs1[128 * 32];
    const int bm0 = blockIdx.x * 128;
    const int y = blockIdx.y;
    if (y == 0)       // vproj = v @ W_in (fp16 head-major), both col-tiles
        gemm_fused_tile<1, true >(v, Tin,   b_in,  vproj, M_TOT, 256, bm0, 0, 128, As, Bs0, Bs1);
    else if (y == 1)  // offh cols 0-255 = q @ Tcomb (fp16)
        gemm_fused_tile<2, true >(q, Tcomb, bcomb, offh,  M_TOT, 384, bm0, 0, 128, As, Bs0, Bs1);
    else              // offh cols 256-383
        gemm_fused_tile<2, false>(q, Tcomb, bcomb, offh,  M_TOT, 384, bm0, 256, 0, As, Bs0, Bs1);
}

// =====================================================================
// Output GEMM, BK=64 (R10, kept -- measured neutral vs BK=32).
// =====================================================================
__global__ __launch_bounds__(256) void gemm_out_kernel(
    const ushort_t* __restrict__ mid, const ushort_t* __restrict__ Tout,
    const float* __restrict__ b_out, float* __restrict__ out)
{
    __shared__ ushort_t As[128 * 64];   // 16 KB
    __shared__ ushort_t Bs[128 * 64];   // 16 KB

    const int tid  = threadIdx.x;
    const int wave = tid >> 6;
    const int lane = tid & 63;
    const int quad = lane >> 4;
    const int l16  = lane & 15;
    const int wm   = (wave >> 1) * 64;
    const int wn   = (wave & 1) * 64;
    const int bm0  = blockIdx.x * 128;
    const int bn0  = blockIdx.y * 128;
    const int M    = M_TOT;

    const int rowt = tid >> 3;          // 0..31 (row within 32-row band)
    const int kc   = (tid & 7) * 8;     // k-element offset 0..56

    const ushort_t* gA[4];
    const ushort_t* gB[4];
    #pragma unroll
    for (int j = 0; j < 4; ++j) {
        int ar = bm0 + rowt + j * 32; if (ar > M - 1) ar = M - 1;
        gA[j] = mid  + (size_t)ar * 256 + kc;
        gB[j] = Tout + (size_t)(bn0 + rowt + j * 32) * 256 + kc;
    }

    floatx4 acc[4][4];
    #pragma unroll
    for (int i = 0; i < 4; ++i)
        #pragma unroll
        for (int j = 0; j < 4; ++j)
            acc[i][j] = (floatx4){0.f, 0.f, 0.f, 0.f};

    for (int kk = 0; kk < 256; kk += 64) {
        #pragma unroll
        for (int j = 0; j < 4; ++j) {
            GLOAD16(gA[j] + kk, As + j * 2048 + wave * 512);
            GLOAD16(gB[j] + kk, Bs + j * 2048 + wave * 512);
        }
        __syncthreads();

        #pragma unroll
        for (int s = 0; s < 2; ++s) {
            short8 af[4], bfr[4];
            #pragma unroll
            for (int mt = 0; mt < 4; ++mt)
                af[mt] = *(const short8*)&As[(wm + mt * 16 + l16) * 64 + s * 32 + quad * 8];
            #pragma unroll
            for (int nt = 0; nt < 4; ++nt)
                bfr[nt] = *(const short8*)&Bs[(wn + nt * 16 + l16) * 64 + s * 32 + quad * 8];
            #pragma unroll
            for (int mt = 0; mt < 4; ++mt)
                #pragma unroll
                for (int nt = 0; nt < 4; ++nt)
                    acc[mt][nt] = __builtin_amdgcn_mfma_f32_16x16x32_bf16(
                        af[mt], bfr[nt], acc[mt][nt], 0, 0, 0);
        }
        __syncthreads();
    }

    #pragma unroll
    for (int mt = 0; mt < 4; ++mt) {
        #pragma unroll
        for (int j = 0; j < 4; ++j) {
            const int row = bm0 + wm + mt * 16 + quad * 4 + j;
            if (row >= M) continue;
            #pragma unroll
            for (int nt = 0; nt < 4; ++nt) {
                const int col = bn0 + wn + nt * 16 + l16;
                out[(size_t)row * 256 + col] = acc[mt][nt][j] + b_out[col];
            }
        }
    }
}

// =====================================================================
// Sampling kernel v11: consumer-indexed handoff, even-bank swizzle.
//  Per sample s (h4 = l>>4, s = l&15, xb = (s>>2)&1), phase 1 writes
//  two int4s {B_r, w_l, B_r+64, w_r} at int4-addr h4*34 + s*2 + (r^xb).
//  The r^xb XOR spreads each write instruction's bank-starts over all
//  8 start positions exactly 8x -> b128 minimum cycles, ZERO excess
//  conflict (enumerated; R9's layout was 4-way on writes).
//  Phase-2 lane (hg,rowr,corner,c4) precomputes two int2 pointers
//  (rowr and rowr^1) and per iter does: 1 ds_read_b64 @ immediate
//  offset + 1 add + 1 gather + 8 FMA.  ZERO cndmask selects (v9 had 4
//  + an extra b128 read).  16 distinct int2 x 2 banks tile all 32
//  banks -> conflict-free reads; 4-lane broadcasts free.
//  Gather addresses / folds / writer mapping / zeroed-pad overread
//  semantics identical to v9.
// =====================================================================
#define ACC8(W, g) { \
    const __half2 h0 = *(const __half2*)&(g).x; \
    const __half2 h1 = *(const __half2*)&(g).y; \
    const __half2 h2 = *(const __half2*)&(g).z; \
    const __half2 h3 = *(const __half2*)&(g).w; \
    a0 = fmaf(W, __low2float(h0),  a0);  a1 = fmaf(W, __high2float(h0), a1); \
    a2 = fmaf(W, __low2float(h1),  a2);  a3 = fmaf(W, __high2float(h1), a3); \
    a4 = fmaf(W, __low2float(h2),  a4);  a5 = fmaf(W, __high2float(h2), a5); \
    a6 = fmaf(W, __low2float(h3),  a6);  a7 = fmaf(W, __high2float(h3), a7); }

__global__ __launch_bounds__(256, 8) void msda_sample_kernel(
    const ushort_t* __restrict__ vproj, const ushort_t* __restrict__ offh,
    const float* __restrict__ p, ushort_t* __restrict__ mid)
{
    // [wave][h4*68 + s*4 + swizzled pair/corner] ; 68 int2 = 34 int4/head
    __shared__ __align__(16) int2 s_pair[4][272];

    const int tid = threadIdx.x;
    const int wv  = tid >> 6;            // wave id 0..3
    const int l   = tid & 63;
    const int idx = blockIdx.x;
    const int b8  = idx & 7;             // XCD id (round-robin assumption)
    const int hh  = b8 >> 2;             // head half: XCD 0-3 -> 0, 4-7 -> 1
    const int qg  = (idx >> 3) * 4 + (b8 & 3);
    const int nq  = qg * 4 + wv;
    const int nb  = (nq >= QN) ? 1 : 0;

    // ---- phase 1: lane = sample (h4 = l>>4, lvl = (l>>2)&3, pt = l&3)
    const size_t orow = (size_t)nq * 384;
    const __half2 o2 = *(const __half2*)&offh[orow + hh * 128 + 2 * l];
    const float2  of = __half22float2(o2);
    const float   lg = __half2float(
        *(const __half*)&offh[orow + 256 + hh * 64 + l]);
    const int     lvl = (l >> 2) & 3;
    const float2  pl  = *(const float2*)&p[(size_t)nq * 8 + lvl * 2];

    // softmax over 16-lane head groups
    float mx = lg;
    #pragma unroll
    for (int m = 8; m; m >>= 1) mx = fmaxf(mx, __shfl_xor(mx, m));
    const float e = __expf(lg - mx);
    float ss = e;
    #pragma unroll
    for (int m = 8; m; m >>= 1) ss += __shfl_xor(ss, m);
    const float wt = e * __builtin_amdgcn_rcpf(ss);

    const int   Wl = 96 >> lvl;                     // H == W per level
    const float fW = (float)Wl;
    const int   st = 12288 - (12288 >> (2 * lvl));  // level start pixel
    const int   h4 = l >> 4;
    const int   h  = hh * 4 + h4;                   // global head

    {
        const float x  = fmaf(pl.x, fW, of.x) - 0.5f;
        const float y  = fmaf(pl.y, fW, of.y) - 0.5f;
        const float xf = floorf(x), yf = floorf(y);
        const float dx = x - xf,    dy = y - yf;
        const int   x0 = (int)xf,   y0 = (int)yf;
        const bool vxl = (unsigned)x0       < (unsigned)Wl;
        const bool vxr = (unsigned)(x0 + 1) < (unsigned)Wl;
        const bool vy0 = (unsigned)y0       < (unsigned)Wl;
        const bool vy1 = (unsigned)(y0 + 1) < (unsigned)Wl;

        const float wxl = vxl ? (1.0f - dx) : (vxr ? dx : 0.0f);
        const float wxr = (vxl && vxr) ? dx : 0.0f;
        const int   xb2 = vxl ? x0 : 0;

        const float wy0f = wt * (1.0f - dy), wy1f = wt * dy;
        const float w_l0 = vy0 ? wxl * wy0f : 0.0f;
        const float w_r0 = vy0 ? wxr * wy0f : 0.0f;
        const float w_l1 = vy1 ? wxl * wy1f : 0.0f;
        const float w_r1 = vy1 ? wxr * wy1f : 0.0f;

        int yc0 = y0;     if (yc0 < 0) yc0 = 0; if (yc0 > Wl - 1) yc0 = Wl - 1;
        int yc1 = y0 + 1; if (yc1 < 0) yc1 = 0; if (yc1 > Wl - 1) yc1 = Wl - 1;

        const int rowb = h * M_TOT + nb * HW_TOT + st + xb2;
        const int B0 = (rowb + yc0 * Wl) << 6;  // byte base, valid pixel
        const int B1 = (rowb + yc1 * Wl) << 6;  // (the +64 chunk of the
                                                //  final pixel reads the
                                                //  zeroed pad with w = 0)
        const int s  = l & 15;
        const int xb = (s >> 2) & 1;
        const int A  = h4 * 34 + s * 2;         // int4 units
        int4* p4 = (int4*)&s_pair[wv][0];
        p4[A + xb]       = (int4){B0, __float_as_int(w_l0),
                                  B0 + 64, __float_as_int(w_r0)};
        p4[A + (xb ^ 1)] = (int4){B1, __float_as_int(w_l1),
                                  B1 + 64, __float_as_int(w_r1)};
    }

    // wave-local LDS handoff: DS ops are in-order per wave; drain lgkm
    // and fence the compiler.  No s_barrier -- waves are independent.
    __builtin_amdgcn_wave_barrier();
    asm volatile("s_waitcnt lgkmcnt(0)" ::: "memory");
    __builtin_amdgcn_wave_barrier();

    // ---- phase 2: lane = (head hg, row rowr, corner, ch-quad c4)
    const int hg     = l >> 4;
    const int rowr   = (l >> 3) & 1;
    const int corner = (l >> 2) & 1;
    const int c4x16  = (l & 3) * 16;     // byte offset within 64B chunk
    const char* __restrict__ vb = (const char*)vproj;
    // pointer for xb=0 samples (t in 0-3, 8-11) and xb=1 (t in 4-7, 12-15)
    const int2* __restrict__ pA = &s_pair[wv][hg * 68 + rowr * 2 + corner];
    const int2* __restrict__ pB = &s_pair[wv][hg * 68 + (rowr ^ 1) * 2 + corner];

    float a0 = 0.f, a1 = 0.f, a2 = 0.f, a3 = 0.f;
    float a4 = 0.f, a5 = 0.f, a6 = 0.f, a7 = 0.f;

    #pragma unroll
    for (int t = 0; t < 16; ++t) {
        const int2 rd = (((t >> 2) & 1) ? pB : pA)[t * 4];  // imm offset
        const float w = __int_as_float(rd.y);
        const uint4 g = *(const uint4*)(vb + (unsigned)(rd.x + c4x16));
        ACC8(w, g);
    }

    // fold corners (bit2) then rows (bit3)
    a0 += __shfl_xor(a0, 4);  a1 += __shfl_xor(a1, 4);
    a2 += __shfl_xor(a2, 4);  a3 += __shfl_xor(a3, 4);
    a4 += __shfl_xor(a4, 4);  a5 += __shfl_xor(a5, 4);
    a6 += __shfl_xor(a6, 4);  a7 += __shfl_xor(a7, 4);
    a0 += __shfl_xor(a0, 8);  a1 += __shfl_xor(a1, 8);
    a2 += __shfl_xor(a2, 8);  a3 += __shfl_xor(a3, 8);
    a4 += __shfl_xor(a4, 8);  a5 += __shfl_xor(a5, 8);
    a6 += __shfl_xor(a6, 8);  a7 += __shfl_xor(a7, 8);

    if ((l & 12) == 0) {                 // 4 writer lanes per head
        ushort_t mv[8] = {f2bf(a0), f2bf(a1), f2bf(a2), f2bf(a3),
                          f2bf(a4), f2bf(a5), f2bf(a6), f2bf(a7)};
        const int col = (hh * 4 + hg) * 32 + (l & 3) * 8;
        *(uint4*)&mid[(size_t)nq * 256 + col] = *(uint4*)mv;
    }
}

// =====================================================================
extern "C" void kernel_launch(void* const* d_in, const int* in_sizes, int n_in,
                              void* d_out, int out_size, void* d_ws, size_t ws_size,
                              hipStream_t stream)
{
    const float* q      = (const float*)d_in[0];
    const float* p      = (const float*)d_in[1];
    const float* v      = (const float*)d_in[2];
    const float* W_off  = (const float*)d_in[3];
    const float* b_off  = (const float*)d_in[4];
    const float* W_attn = (const float*)d_in[5];
    const float* b_attn = (const float*)d_in[6];
    const float* W_in   = (const float*)d_in[7];
    const float* b_in   = (const float*)d_in[8];
    const float* W_out  = (const float*)d_in[9];
    const float* b_out  = (const float*)d_in[10];
    float* out = (float*)d_out;

    const int M = M_TOT;                            // 24480

    // workspace layout.  vproj (fp16 head-major) is followed by a 128B
    // ZEROED pad (sampler overread safety; fp16 zero = 0x0000).
    ushort_t* vproj  = (ushort_t*)d_ws;                          // M*256 fp16 (head-major)
    ushort_t* vpad   = vproj + (size_t)M * 256;                  // 64 ushort = 128B zero pad
    ushort_t* offh   = vpad + 64;                                // M*384 fp16
    ushort_t* mid    = offh + (size_t)M * 384;                   // M*256 bf16
    ushort_t* Tin    = mid + (size_t)M * 256;
    ushort_t* Tcomb  = Tin + 256 * 256;
    ushort_t* Tout   = Tcomb + 384 * 256;
    float*    bcomb  = (float*)(Tout + 256 * 256);

    // 0) weight transposes/fusion + pad zero (small)
    prep_weights_kernel<<<dim3(384), 256, 0, stream>>>(
        W_in, W_off, W_attn, W_out, b_off, b_attn,
        Tin, Tcomb, Tout, bcomb, (int*)vpad);

    // 1) fused convert+projection GEMMs (reads RAW fp32 v/q)
    gemm_proj_kernel<<<dim3(192, 3), 256, 0, stream>>>(
        v, q, Tin, Tcomb, b_in, bcomb, vproj, offh);
    // 2) softmax + bilinear sampling -> bf16 mid (v11 consumer-indexed)
    msda_sample_kernel<<<dim3(12240), 256, 0, stream>>>(vproj, offh, p, mid);
    // 3) out = mid @ W_out + b_out (BK=64)
    gemm_out_kernel<<<dim3(192, 2), 256, 0, stream>>>(mid, Tout, b_out, out);
}

// Round 12
// 180.414 us; speedup vs baseline: 1.0524x; 1.0157x over previous
//
#include <hip/hip_runtime.h>
#include <hip/hip_bf16.h>
#include <hip/hip_fp16.h>
#include <math.h>

// ---- problem constants (structural, from the reference) ----
#define NB      2
#define QN      12240
#define HW_TOT  12240
#define DIMS    256
#define HEADS   8
#define CH      32
#define LEVELS  4
#define POINTS  4
#define M_TOT   (NB * QN)        // 24480

typedef unsigned short ushort_t;
typedef __attribute__((ext_vector_type(8))) short short8;
typedef __attribute__((ext_vector_type(4))) float floatx4;

__device__ __forceinline__ ushort_t f2bf(float f) {
    __hip_bfloat16 h = __float2bfloat16(f);
    return *reinterpret_cast<ushort_t*>(&h);
}
__device__ __forceinline__ ushort_t f2h(float f) {
    __half h = __float2half(f);
    return *reinterpret_cast<ushort_t*>(&h);
}

#define GLOAD16(gp, lp) __builtin_amdgcn_global_load_lds( \
    (const __attribute__((address_space(1))) void*)(gp),  \
    (__attribute__((address_space(3))) void*)(lp), 16, 0, 0)

// =====================================================================
// Weights -> transposed bf16 (small, 384 blocks): Tin/Tout (gi<65536),
// Tcomb [384][256], combined bias, and the 128B zero pad after vproj.
// =====================================================================
__global__ __launch_bounds__(256) void prep_weights_kernel(
    const float* __restrict__ W_in, const float* __restrict__ W_off,
    const float* __restrict__ W_attn, const float* __restrict__ W_out,
    const float* __restrict__ b_off, const float* __restrict__ b_attn,
    ushort_t* __restrict__ Tin, ushort_t* __restrict__ Tcomb,
    ushort_t* __restrict__ Tout, float* __restrict__ bcomb,
    int* __restrict__ vpad)
{
    const int gi = blockIdx.x * 256 + threadIdx.x;   // grid = 384 blocks
    if (gi < 32)  vpad[gi] = 0;                      // 128B zero pad
    if (gi < 384) bcomb[gi] = (gi < 256) ? b_off[gi] : b_attn[gi - 256];
    const int k = gi & 255;                          // coalesced along k
    const int n = gi >> 8;
    if (gi < 65536) {
        Tin[n * 256 + k]  = f2bf(W_in[k * 256 + n]);
        Tout[n * 256 + k] = f2bf(W_out[k * 256 + n]);
    }
    const float val = (n < 256) ? W_off[k * 256 + n]
                                : W_attn[k * 128 + (n - 256)];
    Tcomb[n * 256 + k] = f2bf(val);
}

// =====================================================================
// Fused-convert GEMM tile (R6 single-buffer structure, unchanged).
// CMODE: 1 = FP16 HEAD-MAJOR vproj ((h*M+row)*32+ch), 2 = fp16 row-major.
// =====================================================================
template<int CMODE, bool DUAL>
__device__ __forceinline__ void gemm_fused_tile(
    const float* __restrict__ A32, const ushort_t* __restrict__ BT,
    const float* __restrict__ bias, void* __restrict__ C,
    int M, int Nc, int bm0, int bn0a, int bn0b,
    ushort_t* As, ushort_t* Bs0, ushort_t* Bs1)
{
    const int tid  = threadIdx.x;
    const int wave = tid >> 6;
    const int lane = tid & 63;
    const int quad = lane >> 4;
    const int l16  = lane & 15;
    const int wm   = (wave >> 1) * 64;
    const int wn   = (wave & 1) * 64;

    const int off0 = tid * 16;            // LDS byte offset (linear)
    const int row0 = off0 >> 6;           // 0..63 (64B = 32 bf16/row)
    const int kc0  = (off0 & 63) >> 1;    // element k-offset: 0/8/16/24

    int ar0 = bm0 + row0;      if (ar0 > M - 1) ar0 = M - 1;
    int ar1 = bm0 + row0 + 64; if (ar1 > M - 1) ar1 = M - 1;

    const float*    gA0  = A32 + (size_t)ar0 * 256 + kc0;
    const float*    gA1  = A32 + (size_t)ar1 * 256 + kc0;
    const ushort_t* gb0a = BT + (size_t)(bn0a + row0) * 256 + kc0;
    const ushort_t* gb1a = BT + (size_t)(bn0a + row0 + 64) * 256 + kc0;
    const ushort_t* gb0b = BT + (size_t)(bn0b + row0) * 256 + kc0;
    const ushort_t* gb1b = BT + (size_t)(bn0b + row0 + 64) * 256 + kc0;

    ushort_t* lB0a = Bs0 + wave * 512;
    ushort_t* lB1a = Bs0 + wave * 512 + 2048;
    ushort_t* lB0b = Bs1 + wave * 512;
    ushort_t* lB1b = Bs1 + wave * 512 + 2048;

    floatx4 acc0[4][4], acc1[4][4];
    #pragma unroll
    for (int i = 0; i < 4; ++i)
        #pragma unroll
        for (int j = 0; j < 4; ++j) {
            acc0[i][j] = (floatx4){0.f, 0.f, 0.f, 0.f};
            if (DUAL) acc1[i][j] = (floatx4){0.f, 0.f, 0.f, 0.f};
        }

    for (int kk = 0; kk < 256; kk += 32) {
        GLOAD16(gb0a + kk, lB0a);
        GLOAD16(gb1a + kk, lB1a);
        if (DUAL) {
            GLOAD16(gb0b + kk, lB0b);
            GLOAD16(gb1b + kk, lB1b);
        }
        // A: fp32 -> bf16 reg-staged (each thread: 2 rows x 8 elems)
        {
            const float4 a0 = *(const float4*)(gA0 + kk);
            const float4 a1 = *(const float4*)(gA0 + kk + 4);
            const float4 b0 = *(const float4*)(gA1 + kk);
            const float4 b1 = *(const float4*)(gA1 + kk + 4);
            ushort_t t0[8] = {f2bf(a0.x), f2bf(a0.y), f2bf(a0.z), f2bf(a0.w),
                              f2bf(a1.x), f2bf(a1.y), f2bf(a1.z), f2bf(a1.w)};
            ushort_t t1[8] = {f2bf(b0.x), f2bf(b0.y), f2bf(b0.z), f2bf(b0.w),
                              f2bf(b1.x), f2bf(b1.y), f2bf(b1.z), f2bf(b1.w)};
            *(int4*)&As[tid * 8]        = *(int4*)t0;
            *(int4*)&As[tid * 8 + 2048] = *(int4*)t1;
        }
        __syncthreads();

        short8 af[4], bfa[4], bfb[4];
        #pragma unroll
        for (int mt = 0; mt < 4; ++mt)
            af[mt] = *(const short8*)&As[(wm + mt * 16 + l16) * 32 + quad * 8];
        #pragma unroll
        for (int nt = 0; nt < 4; ++nt) {
            bfa[nt] = *(const short8*)&Bs0[(wn + nt * 16 + l16) * 32 + quad * 8];
            if (DUAL)
                bfb[nt] = *(const short8*)&Bs1[(wn + nt * 16 + l16) * 32 + quad * 8];
        }
        #pragma unroll
        for (int mt = 0; mt < 4; ++mt)
            #pragma unroll
            for (int nt = 0; nt < 4; ++nt) {
                acc0[mt][nt] = __builtin_amdgcn_mfma_f32_16x16x32_bf16(
                    af[mt], bfa[nt], acc0[mt][nt], 0, 0, 0);
                if (DUAL)
                    acc1[mt][nt] = __builtin_amdgcn_mfma_f32_16x16x32_bf16(
                        af[mt], bfb[nt], acc1[mt][nt], 0, 0, 0);
            }
        __syncthreads();
    }

    #pragma unroll
    for (int mt = 0; mt < 4; ++mt) {
        #pragma unroll
        for (int j = 0; j < 4; ++j) {
            const int row = bm0 + wm + mt * 16 + quad * 4 + j;
            if (row >= M) continue;
            #pragma unroll
            for (int nt = 0; nt < 4; ++nt) {
                {
                    const int col = bn0a + wn + nt * 16 + l16;
                    const float val = acc0[mt][nt][j] + bias[col];
                    if (CMODE == 1) {
                        const size_t idx = (((size_t)(col >> 5) * M + row) << 5) + (col & 31);
                        ((ushort_t*)C)[idx] = f2h(val);          // fp16 vproj
                    } else {
                        ((ushort_t*)C)[(size_t)row * Nc + col] = f2h(val);
                    }
                }
                if (DUAL) {
                    const int col = bn0b + wn + nt * 16 + l16;
                    const float val = acc1[mt][nt][j] + bias[col];
                    if (CMODE == 1) {
                        const size_t idx = (((size_t)(col >> 5) * M + row) << 5) + (col & 31);
                        ((ushort_t*)C)[idx] = f2h(val);          // fp16 vproj
                    } else {
                        ((ushort_t*)C)[(size_t)row * Nc + col] = f2h(val);
                    }
                }
            }
        }
    }
}

__global__ __launch_bounds__(256) void gemm_proj_kernel(
    const float* __restrict__ v, const float* __restrict__ q,
    const ushort_t* __restrict__ Tin, const ushort_t* __restrict__ Tcomb,
    const float* __restrict__ b_in, const float* __restrict__ bcomb,
    ushort_t* __restrict__ vproj, ushort_t* __restrict__ offh)
{
    __shared__ ushort_t As [128 * 32];
    __shared__ ushort_t Bs0[128 * 32];
    __shared__ ushort_t Bs1[128 * 32];
    const int bm0 = blockIdx.x * 128;
    const int y = blockIdx.y;
    if (y == 0)       // vproj = v @ W_in (fp16 head-major), both col-tiles
        gemm_fused_tile<1, true >(v, Tin,   b_in,  vproj, M_TOT, 256, bm0, 0, 128, As, Bs0, Bs1);
    else if (y == 1)  // offh cols 0-255 = q @ Tcomb (fp16)
        gemm_fused_tile<2, true >(q, Tcomb, bcomb, offh,  M_TOT, 384, bm0, 0, 128, As, Bs0, Bs1);
    else              // offh cols 256-383
        gemm_fused_tile<2, false>(q, Tcomb, bcomb, offh,  M_TOT, 384, bm0, 256, 0, As, Bs0, Bs1);
}

// =====================================================================
// Output GEMM, BK=64 (R10, kept -- measured neutral vs BK=32).
// =====================================================================
__global__ __launch_bounds__(256) void gemm_out_kernel(
    const ushort_t* __restrict__ mid, const ushort_t* __restrict__ Tout,
    const float* __restrict__ b_out, float* __restrict__ out)
{
    __shared__ ushort_t As[128 * 64];   // 16 KB
    __shared__ ushort_t Bs[128 * 64];   // 16 KB

    const int tid  = threadIdx.x;
    const int wave = tid >> 6;
    const int lane = tid & 63;
    const int quad = lane >> 4;
    const int l16  = lane & 15;
    const int wm   = (wave >> 1) * 64;
    const int wn   = (wave & 1) * 64;
    const int bm0  = blockIdx.x * 128;
    const int bn0  = blockIdx.y * 128;
    const int M    = M_TOT;

    const int rowt = tid >> 3;          // 0..31 (row within 32-row band)
    const int kc   = (tid & 7) * 8;     // k-element offset 0..56

    const ushort_t* gA[4];
    const ushort_t* gB[4];
    #pragma unroll
    for (int j = 0; j < 4; ++j) {
        int ar = bm0 + rowt + j * 32; if (ar > M - 1) ar = M - 1;
        gA[j] = mid  + (size_t)ar * 256 + kc;
        gB[j] = Tout + (size_t)(bn0 + rowt + j * 32) * 256 + kc;
    }

    floatx4 acc[4][4];
    #pragma unroll
    for (int i = 0; i < 4; ++i)
        #pragma unroll
        for (int j = 0; j < 4; ++j)
            acc[i][j] = (floatx4){0.f, 0.f, 0.f, 0.f};

    for (int kk = 0; kk < 256; kk += 64) {
        #pragma unroll
        for (int j = 0; j < 4; ++j) {
            GLOAD16(gA[j] + kk, As + j * 2048 + wave * 512);
            GLOAD16(gB[j] + kk, Bs + j * 2048 + wave * 512);
        }
        __syncthreads();

        #pragma unroll
        for (int s = 0; s < 2; ++s) {
            short8 af[4], bfr[4];
            #pragma unroll
            for (int mt = 0; mt < 4; ++mt)
                af[mt] = *(const short8*)&As[(wm + mt * 16 + l16) * 64 + s * 32 + quad * 8];
            #pragma unroll
            for (int nt = 0; nt < 4; ++nt)
                bfr[nt] = *(const short8*)&Bs[(wn + nt * 16 + l16) * 64 + s * 32 + quad * 8];
            #pragma unroll
            for (int mt = 0; mt < 4; ++mt)
                #pragma unroll
                for (int nt = 0; nt < 4; ++nt)
                    acc[mt][nt] = __builtin_amdgcn_mfma_f32_16x16x32_bf16(
                        af[mt], bfr[nt], acc[mt][nt], 0, 0, 0);
        }
        __syncthreads();
    }

    #pragma unroll
    for (int mt = 0; mt < 4; ++mt) {
        #pragma unroll
        for (int j = 0; j < 4; ++j) {
            const int row = bm0 + wm + mt * 16 + quad * 4 + j;
            if (row >= M) continue;
            #pragma unroll
            for (int nt = 0; nt < 4; ++nt) {
                const int col = bn0 + wn + nt * 16 + l16;
                out[(size_t)row * 256 + col] = acc[mt][nt][j] + b_out[col];
            }
        }
    }
}

// =====================================================================
// Sampling kernel v12: v11 handoff (consumer-indexed, even-bank
// swizzle, 0 conflicts measured) + EXPLICIT 2-deep x 4-wide gather
// pipeline in phase 2.  R11 showed VGPR_Count=32 -> only ~1 gather in
// flight per wave -> L2 latency exposed.  Named register batches keep
// 8 gathers outstanding; launch_bounds 8->6 waves/EU raises the VGPR
// budget to ~85 so the pipeline isn't spilled away.
// =====================================================================
#define ACC8(W, g) { \
    const __half2 h0 = *(const __half2*)&(g).x; \
    const __half2 h1 = *(const __half2*)&(g).y; \
    const __half2 h2 = *(const __half2*)&(g).z; \
    const __half2 h3 = *(const __half2*)&(g).w; \
    a0 = fmaf(W, __low2float(h0),  a0);  a1 = fmaf(W, __high2float(h0), a1); \
    a2 = fmaf(W, __low2float(h1),  a2);  a3 = fmaf(W, __high2float(h1), a3); \
    a4 = fmaf(W, __low2float(h2),  a4);  a5 = fmaf(W, __high2float(h2), a5); \
    a6 = fmaf(W, __low2float(h3),  a6);  a7 = fmaf(W, __high2float(h3), a7); }

#define LDG(dst, rr) dst = *(const uint4*)(vb + (unsigned)((rr).x + c4x16))

__global__ __launch_bounds__(256, 6) void msda_sample_kernel(
    const ushort_t* __restrict__ vproj, const ushort_t* __restrict__ offh,
    const float* __restrict__ p, ushort_t* __restrict__ mid)
{
    // [wave][h4*68 + s*4 + swizzled pair/corner] ; 68 int2 = 34 int4/head
    __shared__ __align__(16) int2 s_pair[4][272];

    const int tid = threadIdx.x;
    const int wv  = tid >> 6;            // wave id 0..3
    const int l   = tid & 63;
    const int idx = blockIdx.x;
    const int b8  = idx & 7;             // XCD id (round-robin assumption)
    const int hh  = b8 >> 2;             // head half: XCD 0-3 -> 0, 4-7 -> 1
    const int qg  = (idx >> 3) * 4 + (b8 & 3);
    const int nq  = qg * 4 + wv;
    const int nb  = (nq >= QN) ? 1 : 0;

    // ---- phase 1: lane = sample (h4 = l>>4, lvl = (l>>2)&3, pt = l&3)
    const size_t orow = (size_t)nq * 384;
    const __half2 o2 = *(const __half2*)&offh[orow + hh * 128 + 2 * l];
    const float2  of = __half22float2(o2);
    const float   lg = __half2float(
        *(const __half*)&offh[orow + 256 + hh * 64 + l]);
    const int     lvl = (l >> 2) & 3;
    const float2  pl  = *(const float2*)&p[(size_t)nq * 8 + lvl * 2];

    // softmax over 16-lane head groups
    float mx = lg;
    #pragma unroll
    for (int m = 8; m; m >>= 1) mx = fmaxf(mx, __shfl_xor(mx, m));
    const float e = __expf(lg - mx);
    float ss = e;
    #pragma unroll
    for (int m = 8; m; m >>= 1) ss += __shfl_xor(ss, m);
    const float wt = e * __builtin_amdgcn_rcpf(ss);

    const int   Wl = 96 >> lvl;                     // H == W per level
    const float fW = (float)Wl;
    const int   st = 12288 - (12288 >> (2 * lvl));  // level start pixel
    const int   h4 = l >> 4;
    const int   h  = hh * 4 + h4;                   // global head

    {
        const float x  = fmaf(pl.x, fW, of.x) - 0.5f;
        const float y  = fmaf(pl.y, fW, of.y) - 0.5f;
        const float xf = floorf(x), yf = floorf(y);
        const float dx = x - xf,    dy = y - yf;
        const int   x0 = (int)xf,   y0 = (int)yf;
        const bool vxl = (unsigned)x0       < (unsigned)Wl;
        const bool vxr = (unsigned)(x0 + 1) < (unsigned)Wl;
        const bool vy0 = (unsigned)y0       < (unsigned)Wl;
        const bool vy1 = (unsigned)(y0 + 1) < (unsigned)Wl;

        const float wxl = vxl ? (1.0f - dx) : (vxr ? dx : 0.0f);
        const float wxr = (vxl && vxr) ? dx : 0.0f;
        const int   xb2 = vxl ? x0 : 0;

        const float wy0f = wt * (1.0f - dy), wy1f = wt * dy;
        const float w_l0 = vy0 ? wxl * wy0f : 0.0f;
        const float w_r0 = vy0 ? wxr * wy0f : 0.0f;
        const float w_l1 = vy1 ? wxl * wy1f : 0.0f;
        const float w_r1 = vy1 ? wxr * wy1f : 0.0f;

        int yc0 = y0;     if (yc0 < 0) yc0 = 0; if (yc0 > Wl - 1) yc0 = Wl - 1;
        int yc1 = y0 + 1; if (yc1 < 0) yc1 = 0; if (yc1 > Wl - 1) yc1 = Wl - 1;

        const int rowb = h * M_TOT + nb * HW_TOT + st + xb2;
        const int B0 = (rowb + yc0 * Wl) << 6;  // byte base, valid pixel
        const int B1 = (rowb + yc1 * Wl) << 6;  // (the +64 chunk of the
                                                //  final pixel reads the
                                                //  zeroed pad with w = 0)
        const int s  = l & 15;
        const int xb = (s >> 2) & 1;
        const int A  = h4 * 34 + s * 2;         // int4 units
        int4* p4 = (int4*)&s_pair[wv][0];
        p4[A + xb]       = (int4){B0, __float_as_int(w_l0),
                                  B0 + 64, __float_as_int(w_r0)};
        p4[A + (xb ^ 1)] = (int4){B1, __float_as_int(w_l1),
                                  B1 + 64, __float_as_int(w_r1)};
    }

    // wave-local LDS handoff: DS ops are in-order per wave; drain lgkm
    // and fence the compiler.  No s_barrier -- waves are independent.
    __builtin_amdgcn_wave_barrier();
    asm volatile("s_waitcnt lgkmcnt(0)" ::: "memory");
    __builtin_amdgcn_wave_barrier();

    // ---- phase 2: lane = (head hg, row rowr, corner, ch-quad c4)
    const int hg     = l >> 4;
    const int rowr   = (l >> 3) & 1;
    const int corner = (l >> 2) & 1;
    const int c4x16  = (l & 3) * 16;     // byte offset within 64B chunk
    const char* __restrict__ vb = (const char*)vproj;
    // pointer for xb=0 samples (t 0-3, 8-11) and xb=1 (t 4-7, 12-15)
    const int2* __restrict__ pA = &s_pair[wv][hg * 68 + rowr * 2 + corner];
    const int2* __restrict__ pB = &s_pair[wv][hg * 68 + (rowr ^ 1) * 2 + corner];

    float a0 = 0.f, a1 = 0.f, a2 = 0.f, a3 = 0.f;
    float a4 = 0.f, a5 = 0.f, a6 = 0.f, a7 = 0.f;

    // 2-deep x 4-wide pipeline: 8 gathers in flight at steady state.
    int2 rA0 = pA[0],  rA1 = pA[4],  rA2 = pA[8],  rA3 = pA[12];
    int2 rB0 = pB[16], rB1 = pB[20], rB2 = pB[24], rB3 = pB[28];
    uint4 gA0, gA1, gA2, gA3, gB0, gB1, gB2, gB3;
    LDG(gA0, rA0); LDG(gA1, rA1); LDG(gA2, rA2); LDG(gA3, rA3);
    LDG(gB0, rB0); LDG(gB1, rB1); LDG(gB2, rB2); LDG(gB3, rB3);

    // consume batch 0 (t=0..3), refill with batch 2 (t=8..11)
    ACC8(__int_as_float(rA0.y), gA0);
    ACC8(__int_as_float(rA1.y), gA1);
    ACC8(__int_as_float(rA2.y), gA2);
    ACC8(__int_as_float(rA3.y), gA3);
    rA0 = pA[32]; rA1 = pA[36]; rA2 = pA[40]; rA3 = pA[44];
    LDG(gA0, rA0); LDG(gA1, rA1); LDG(gA2, rA2); LDG(gA3, rA3);

    // consume batch 1 (t=4..7), refill with batch 3 (t=12..15)
    ACC8(__int_as_float(rB0.y), gB0);
    ACC8(__int_as_float(rB1.y), gB1);
    ACC8(__int_as_float(rB2.y), gB2);
    ACC8(__int_as_float(rB3.y), gB3);
    rB0 = pB[48]; rB1 = pB[52]; rB2 = pB[56]; rB3 = pB[60];
    LDG(gB0, rB0); LDG(gB1, rB1); LDG(gB2, rB2); LDG(gB3, rB3);

    // consume batch 2 (t=8..11)
    ACC8(__int_as_float(rA0.y), gA0);
    ACC8(__int_as_float(rA1.y), gA1);
    ACC8(__int_as_float(rA2.y), gA2);
    ACC8(__int_as_float(rA3.y), gA3);

    // consume batch 3 (t=12..15)
    ACC8(__int_as_float(rB0.y), gB0);
    ACC8(__int_as_float(rB1.y), gB1);
    ACC8(__int_as_float(rB2.y), gB2);
    ACC8(__int_as_float(rB3.y), gB3);

    // fold corners (bit2) then rows (bit3)
    a0 += __shfl_xor(a0, 4);  a1 += __shfl_xor(a1, 4);
    a2 += __shfl_xor(a2, 4);  a3 += __shfl_xor(a3, 4);
    a4 += __shfl_xor(a4, 4);  a5 += __shfl_xor(a5, 4);
    a6 += __shfl_xor(a6, 4);  a7 += __shfl_xor(a7, 4);
    a0 += __shfl_xor(a0, 8);  a1 += __shfl_xor(a1, 8);
    a2 += __shfl_xor(a2, 8);  a3 += __shfl_xor(a3, 8);
    a4 += __shfl_xor(a4, 8);  a5 += __shfl_xor(a5, 8);
    a6 += __shfl_xor(a6, 8);  a7 += __shfl_xor(a7, 8);

    if ((l & 12) == 0) {                 // 4 writer lanes per head
        ushort_t mv[8] = {f2bf(a0), f2bf(a1), f2bf(a2), f2bf(a3),
                          f2bf(a4), f2bf(a5), f2bf(a6), f2bf(a7)};
        const int col = (hh * 4 + hg) * 32 + (l & 3) * 8;
        *(uint4*)&mid[(size_t)nq * 256 + col] = *(uint4*)mv;
    }
}

// =====================================================================
extern "C" void kernel_launch(void* const* d_in, const int* in_sizes, int n_in,
                              void* d_out, int out_size, void* d_ws, size_t ws_size,
                              hipStream_t stream)
{
    const float* q      = (const float*)d_in[0];
    const float* p      = (const float*)d_in[1];
    const float* v      = (const float*)d_in[2];
    const float* W_off  = (const float*)d_in[3];
    const float* b_off  = (const float*)d_in[4];
    const float* W_attn = (const float*)d_in[5];
    const float* b_attn = (const float*)d_in[6];
    const float* W_in   = (const float*)d_in[7];
    const float* b_in   = (const float*)d_in[8];
    const float* W_out  = (const float*)d_in[9];
    const float* b_out  = (const float*)d_in[10];
    float* out = (float*)d_out;

    const int M = M_TOT;                            // 24480

    // workspace layout.  vproj (fp16 head-major) is followed by a 128B
    // ZEROED pad (sampler overread safety; fp16 zero = 0x0000).
    ushort_t* vproj  = (ushort_t*)d_ws;                          // M*256 fp16 (head-major)
    ushort_t* vpad   = vproj + (size_t)M * 256;                  // 64 ushort = 128B zero pad
    ushort_t* offh   = vpad + 64;                                // M*384 fp16
    ushort_t* mid    = offh + (size_t)M * 384;                   // M*256 bf16
    ushort_t* Tin    = mid + (size_t)M * 256;
    ushort_t* Tcomb  = Tin + 256 * 256;
    ushort_t* Tout   = Tcomb + 384 * 256;
    float*    bcomb  = (float*)(Tout + 256 * 256);

    // 0) weight transposes/fusion + pad zero (small)
    prep_weights_kernel<<<dim3(384), 256, 0, stream>>>(
        W_in, W_off, W_attn, W_out, b_off, b_attn,
        Tin, Tcomb, Tout, bcomb, (int*)vpad);

    // 1) fused convert+projection GEMMs (reads RAW fp32 v/q)
    gemm_proj_kernel<<<dim3(192, 3), 256, 0, stream>>>(
        v, q, Tin, Tcomb, b_in, bcomb, vproj, offh);
    // 2) softmax + bilinear sampling -> bf16 mid (v12 pipelined gathers)
    msda_sample_kernel<<<dim3(12240), 256, 0, stream>>>(vproj, offh, p, mid);
    // 3) out = mid @ W_out + b_out (BK=64)
    gemm_out_kernel<<<dim3(192, 2), 256, 0, stream>>>(mid, Tout, b_out, out);
}